// Round 1
// baseline (146.939 us; speedup 1.0000x reference)
//
#include <hip/hip_runtime.h>

// CRF loss: sum_b(forward_score[b] - gold_score[b]).  B=512, T=1024, L=32.
//
// R9 = R8b structure with doubled wave parallelism (latency-bound fix).
// rocprof R8b: MfmaUtil 21 / VALUBusy 44 / Occupancy 32 / HBM 12% -> no pipe
// saturated; per-wave serial chain (128 steps) starves 4 waves/SIMD.
// - 16 waves/block (1024 thr), 64 steps/wave -> 2 blocks/CU = 8 waves/SIMD.
//   Same total VALU/MFMA work, 2x the latency-hiding pool.
// - LDS can't hold 16 f32 chunk matrices (67.6KB > 64KB static limit):
//   two-phase combine. Waves 0-7 deposit M_c -> barrier -> wave 0 folds
//   chunks 0-7 into q -> barrier -> waves 8-15 deposit into the SAME 8
//   slots -> barrier -> wave 0 folds chunks 8-15 and finalizes.
//   q/Cq/gold live in wave-0 registers across phases; combine stays exact f32.
// - Skew now staggers SIMD-siblings via w>>2 (w&3 would phase-lock the four
//   same-SIMD waves of a 16-wave block).
// Everything else identical to R8b (proven exact): sigma-permuted E, acc->B
// direct feed, f32x2 v_pk_mul diet, ring-8 refill with tail split, renorm
// every 4 steps via proxy exponent of M[2][0] with last e un-applied.

typedef float  f32x16 __attribute__((ext_vector_type(16)));
typedef short  s16x8  __attribute__((ext_vector_type(8)));
typedef float  f32x2  __attribute__((ext_vector_type(2)));

#define TT 1024
#define LL 32
#define BB 512
#define NW 16          // waves per block
#define CL 64          // steps per wave
#define NCH 8          // LDS-resident chunk matrices per combine phase
#define MS 33

union Frag { s16x8 v; unsigned u[4]; };

// pack two f32 -> u32 holding 2 bf16 (truncation): lo in [15:0], hi in [31:16]
__device__ __forceinline__ unsigned pack_bf16(float lo, float hi) {
    return __builtin_amdgcn_perm(__float_as_uint(hi), __float_as_uint(lo), 0x07060302u);
}

__device__ __forceinline__ void skew_sleep(int n) {
    switch (n & 3) {
        case 1: __builtin_amdgcn_s_sleep(1); break;
        case 2: __builtin_amdgcn_s_sleep(2); break;
        case 3: __builtin_amdgcn_s_sleep(3); break;
        default: break;
    }
}

__global__ __launch_bounds__(NW * 64, 8) void crf_fused_kernel(
    const float* __restrict__ emission,    // [B, T, L]
    const int*   __restrict__ label_ids,   // [B, T]
    const float* __restrict__ transitions, // [L, L]
    float*       __restrict__ out)         // [1], pre-zeroed
{
    __shared__ __align__(16) float shM[NCH][32 * MS];   // 33,792 B
    __shared__ float shQ[2][64];
    __shared__ float tgArr[NW];
    __shared__ int   capArr[NW];

    const int tid  = threadIdx.x;
    const int w    = tid >> 6;             // wave id = chunk id (0..15)
    const int lane = tid & 63;
    const int j    = lane & 31;            // A row m / C-D col n
    const int h    = lane >> 5;            // k-half
    const int b    = blockIdx.x;
    const int t0   = w * CL;

    const int*   labB = label_ids + b * TT + t0;
    const float* emB  = emission + ((size_t)b * TT + t0) * LL + j;

    // ---- gold score partial (transitions + emission gather), preamble ----
    {
        float g = 0.0f;
        int tt = t0 + lane;                // CL == 64: one lane-pass per wave
        int l1 = labB[lane];
        int l0 = (tt == 0) ? 0 : label_ids[b * TT + tt - 1];   // SOS at -1
        g += transitions[(l1 << 5) + l0];
        g += emission[((size_t)b * TT + tt) * LL + l1];
        if (tt == TT - 1) g += transitions[32 + l1];           // trans[END,last]
#pragma unroll
        for (int m = 32; m >= 1; m >>= 1) g += __shfl_xor(g, m, 64);
        if (lane == 0) tgArr[w] = g;
    }

    // ---- E, sigma-permuted cols, as f32x2 pairs for v_pk_mul_f32 ----
    const float* trow = transitions + j * 32;
    f32x2 E0v[4], E1v[4];
#pragma unroll
    for (int p = 0; p < 4; ++p) {
        int c0 = ((2 * p) & 3)     + 8 * ((2 * p) >> 2)     + 4 * h;
        int c1 = ((2 * p + 1) & 3) + 8 * ((2 * p + 1) >> 2) + 4 * h;
        E0v[p][0] = __expf(trow[c0]);      E0v[p][1] = __expf(trow[c1]);
        E1v[p][0] = __expf(trow[16 + c0]); E1v[p][1] = __expf(trow[16 + c1]);
    }

    // ---- B = identity in sigma layout (bf16 1.0 = 0x3F80) ----
    Frag B0, B1;
#pragma unroll
    for (int i = 0; i < 8; ++i) {
        int row = (i & 3) + 8 * (i >> 2) + 4 * h;
        B0.v[i] = (short)((row == j)      ? 0x3F80 : 0);
        B1.v[i] = (short)((row + 16 == j) ? 0x3F80 : 0);
    }

    f32x16 zc, acc;
#pragma unroll
    for (int i = 0; i < 16; ++i) zc[i] = 0.0f;

    float ring[8];
#pragma unroll
    for (int s = 0; s < 8; ++s) ring[s] = emB[s * LL];

    float sc = 1.0f;
    int   Cap = 0, elast = 0;

    // ---- de-phase same-SIMD waves (one-time, s_sleep = 64*N cyc) ----
    skew_sleep((w >> 2) + ((blockIdx.x & 1) << 1));

    // one recurrence step; refill only when told (tail has none)
    auto step = [&](int k, int s, bool refill) {
        float feat = ring[k];
        float fs = ((k & 3) == 0) ? (__expf(feat) * sc) : __expf(feat);
        f32x2 fs2; fs2[0] = fs; fs2[1] = fs;

        Frag A0, A1;
#pragma unroll
        for (int p = 0; p < 4; ++p) {
            f32x2 a = fs2 * E0v[p];
            f32x2 c = fs2 * E1v[p];
            A0.u[p] = pack_bf16(a[0], a[1]);
            A1.u[p] = pack_bf16(c[0], c[1]);
        }

        acc = __builtin_amdgcn_mfma_f32_32x32x16_bf16(A0.v, B0.v, zc, 0, 0, 0);
        acc = __builtin_amdgcn_mfma_f32_32x32x16_bf16(A1.v, B1.v, acc, 0, 0, 0);

        if ((k & 3) == 3) {                // group-end renorm (proxy M[2][0])
            int pb = __builtin_amdgcn_readlane(__float_as_int(acc[2]), 0);
            int e  = ((pb >> 23) & 0xff) - 127;
            sc = __int_as_float((127 - e) << 23);   // exact 2^-e
            Cap += e;
            elast = e;
        }

        if (refill) ring[k] = emB[(s + 8) * LL];

        // next B operand: direct reg feed (sigma layout), pack only
#pragma unroll
        for (int p = 0; p < 4; ++p) {
            B0.u[p] = pack_bf16(acc[2 * p],     acc[2 * p + 1]);
            B1.u[p] = pack_bf16(acc[8 + 2 * p], acc[9 + 2 * p]);
        }
    };

    for (int s0 = 0; s0 < CL - 8; s0 += 8) {
#pragma unroll
        for (int k = 0; k < 8; ++k) step(k, s0 + k, true);
    }
#pragma unroll
    for (int k = 0; k < 8; ++k) step(k, CL - 8 + k, false);

    Cap -= elast;                          // final measured e never applied

    if (lane == 0) capArr[w] = Cap;

    // ---- phase A: waves 0-7 deposit M_c (f32, padded -> conflict-free) ----
    if (w < NCH) {
#pragma unroll
        for (int r = 0; r < 16; ++r) {
            int row = (r & 3) + 8 * (r >> 2) + 4 * h;
            shM[w][row * MS + j] = acc[r];
        }
    }

    // wave-0 combine state (registers persist across both phases)
    const float Eend = __expf(transitions[32 + j]);   // exp(trans[END][j])
    float q    = (j == 0) ? 1.0f : 0.0f;              // one-hot SOS
    int   Cq   = 0;
    float gold = 0.0f;

    auto combine8 = [&](int base) {
#pragma unroll
        for (int c = 0; c < NCH; ++c) {
            shQ[c & 1][lane] = q;
            asm volatile("s_waitcnt lgkmcnt(0)" ::: "memory");
            __builtin_amdgcn_wave_barrier();
            const float* Mrow = &shM[c][j * MS];
            const float* qv   = &shQ[c & 1][h * 32];
            float a0 = 0.f, a1 = 0.f, a2 = 0.f, a3 = 0.f;
#pragma unroll
            for (int i = 0; i < 32; i += 4) {
                a0 = fmaf(Mrow[i],     qv[i],     a0);
                a1 = fmaf(Mrow[i + 1], qv[i + 1], a1);
                a2 = fmaf(Mrow[i + 2], qv[i + 2], a2);
                a3 = fmaf(Mrow[i + 3], qv[i + 3], a3);
            }
            float qn = (a0 + a1) + (a2 + a3);
            int pb = __builtin_amdgcn_readlane(__float_as_int(qn), 2);
            int e  = ((pb >> 23) & 0xff) - 127;
            qn *= __int_as_float((127 - e) << 23);        // exact 2^-e
            Cq += e + capArr[base + c];
            gold += tgArr[base + c];
            q = qn;
        }
    };

    __syncthreads();

    if (w == 0) combine8(0);               // fold chunks 0..7

    __syncthreads();

    // ---- phase B: waves 8-15 deposit into the same 8 slots ----
    if (w >= NCH) {
#pragma unroll
        for (int r = 0; r < 16; ++r) {
            int row = (r & 3) + 8 * (r >> 2) + 4 * h;
            shM[w - NCH][row * MS + j] = acc[r];
        }
    }

    __syncthreads();

    if (w == 0) {
        combine8(NCH);                     // fold chunks 8..15

        float v = q * Eend;
#pragma unroll
        for (int m = 16; m >= 1; m >>= 1) v += __shfl_xor(v, m, 32);
        float fwd = __logf(v) + (float)Cq * 0.69314718055994531f;

        if (lane == 0) atomicAdd(out, fwd - gold);
    }
}

extern "C" void kernel_launch(void* const* d_in, const int* in_sizes, int n_in,
                              void* d_out, int out_size, void* d_ws, size_t ws_size,
                              hipStream_t stream)
{
    const float* emission    = (const float*)d_in[0];
    const int*   label_ids   = (const int*)d_in[1];
    const float* transitions = (const float*)d_in[2];
    float* out = (float*)d_out;

    (void)hipMemsetAsync(out, 0, sizeof(float), stream);
    crf_fused_kernel<<<BB, NW * 64, 0, stream>>>(emission, label_ids, transitions, out);
}

// Round 2
// 139.317 us; speedup vs baseline: 1.0547x; 1.0547x over previous
//
#include <hip/hip_runtime.h>

// CRF loss: sum_b(forward_score[b] - gold_score[b]).  B=512, T=1024, L=32.
//
// R10 = R8b structure + DUAL independent chains per wave (ILP fix).
// Post-mortem R9: forcing 8 waves/SIMD via __launch_bounds__(1024,8) capped
// VGPRs at 64 -> spills (WRITE_SIZE 16B -> 20.9MB, VALUBusy fell). Occupancy
// axis is register-walled.  R10 instead doubles *in-wave* ILP: each wave runs
// TWO independent 64-step recurrence chains (chunks 2w, 2w+1), interleaved.
// Chain B's VALU/MFMA fills chain A's MFMA/exp stall windows; dual state
// (~+50 VGPR) fits the 128-VGPR cap of launch_bounds(512,4) -> no spill.
// - E matrix (16 regs) and zc (16) shared between chains.
// - 16 chunks/block -> two-phase combine reusing 8 LDS slots (proven R9):
//   waves 0-3 deposit chunks 0..7 -> wave 0 folds -> waves 4-7 deposit
//   chunks 8..15 into same slots -> wave 0 folds + finalize.
// Everything else identical to R8b (proven exact): sigma-permuted E, acc->B
// direct feed, f32x2 v_pk_mul diet, ring-8 refill with tail split, renorm
// every 4 steps via proxy exponent of M[2][0] with last e un-applied.

typedef float  f32x16 __attribute__((ext_vector_type(16)));
typedef short  s16x8  __attribute__((ext_vector_type(8)));
typedef float  f32x2  __attribute__((ext_vector_type(2)));

#define TT 1024
#define LL 32
#define BB 512
#define NW 8           // waves per block
#define CL 64          // steps per chain (2 chains per wave)
#define NCH 8          // LDS chunk slots per combine phase
#define MS 33

union Frag { s16x8 v; unsigned u[4]; };

// pack two f32 -> u32 holding 2 bf16 (truncation): lo in [15:0], hi in [31:16]
__device__ __forceinline__ unsigned pack_bf16(float lo, float hi) {
    return __builtin_amdgcn_perm(__float_as_uint(hi), __float_as_uint(lo), 0x07060302u);
}

__device__ __forceinline__ void skew_sleep(int n) {
    switch (n & 3) {
        case 1: __builtin_amdgcn_s_sleep(1); break;
        case 2: __builtin_amdgcn_s_sleep(2); break;
        case 3: __builtin_amdgcn_s_sleep(3); break;
        default: break;
    }
}

__global__ __launch_bounds__(NW * 64, 4) void crf_fused_kernel(
    const float* __restrict__ emission,    // [B, T, L]
    const int*   __restrict__ label_ids,   // [B, T]
    const float* __restrict__ transitions, // [L, L]
    float*       __restrict__ out)         // [1], pre-zeroed
{
    __shared__ __align__(16) float shM[NCH][32 * MS];   // 33,792 B
    __shared__ float shQ[2][64];
    __shared__ float tgArr[NW];
    __shared__ int   capArr[2 * NW];

    const int tid  = threadIdx.x;
    const int w    = tid >> 6;             // wave id (0..7)
    const int lane = tid & 63;
    const int j    = lane & 31;            // A row m / C-D col n
    const int h    = lane >> 5;            // k-half
    const int b    = blockIdx.x;
    const int t0   = w * (2 * CL);         // 128 timesteps per wave (2 chains)

    // ---- gold score partial (transitions + emission gather), preamble ----
    {
        const int* labB = label_ids + b * TT + t0;
        float g = 0.0f;
#pragma unroll
        for (int u = 0; u < 2; ++u) {
            int tt = t0 + 64 * u + lane;
            int l1 = labB[64 * u + lane];
            int l0 = (tt == 0) ? 0 : label_ids[b * TT + tt - 1];   // SOS at -1
            g += transitions[(l1 << 5) + l0];
            g += emission[((size_t)b * TT + tt) * LL + l1];
            if (tt == TT - 1) g += transitions[32 + l1];           // trans[END,last]
        }
#pragma unroll
        for (int m = 32; m >= 1; m >>= 1) g += __shfl_xor(g, m, 64);
        if (lane == 0) tgArr[w] = g;
    }

    // ---- E, sigma-permuted cols, as f32x2 pairs (shared by both chains) ----
    const float* trow = transitions + j * 32;
    f32x2 E0v[4], E1v[4];
#pragma unroll
    for (int p = 0; p < 4; ++p) {
        int c0 = ((2 * p) & 3)     + 8 * ((2 * p) >> 2)     + 4 * h;
        int c1 = ((2 * p + 1) & 3) + 8 * ((2 * p + 1) >> 2) + 4 * h;
        E0v[p][0] = __expf(trow[c0]);      E0v[p][1] = __expf(trow[c1]);
        E1v[p][0] = __expf(trow[16 + c0]); E1v[p][1] = __expf(trow[16 + c1]);
    }

    // ---- B = identity in sigma layout (bf16 1.0 = 0x3F80), per chain ----
    Frag B0a, B1a, B0b, B1b;
#pragma unroll
    for (int i = 0; i < 8; ++i) {
        int row = (i & 3) + 8 * (i >> 2) + 4 * h;
        short lo = (short)((row == j)      ? 0x3F80 : 0);
        short hi = (short)((row + 16 == j) ? 0x3F80 : 0);
        B0a.v[i] = lo;  B1a.v[i] = hi;
        B0b.v[i] = lo;  B1b.v[i] = hi;
    }

    f32x16 zc, accA, accB;
#pragma unroll
    for (int i = 0; i < 16; ++i) zc[i] = 0.0f;

    const float* emA = emission + ((size_t)b * TT + t0) * LL + j;
    const float* emBp = emA + (size_t)CL * LL;     // chain B: t0 + 64

    float ringA[8], ringB[8];
#pragma unroll
    for (int s = 0; s < 8; ++s) { ringA[s] = emA[s * LL]; ringB[s] = emBp[s * LL]; }

    float scA = 1.0f, scB = 1.0f;
    int   CapA = 0, elA = 0, CapB = 0, elB = 0;

    // ---- de-phase the 4 waves/SIMD (one-time, s_sleep = 64*N cyc) ----
    skew_sleep(w + ((blockIdx.x & 1) << 1));

    // one recurrence step on one chain; refill only when told (tail has none)
    auto step = [&](Frag& B0, Frag& B1, f32x16& acc, auto& ring, float& sc,
                    int& Cap, int& elast, const float* em, int k, int s, bool refill) {
        float feat = ring[k];
        float fs = ((k & 3) == 0) ? (__expf(feat) * sc) : __expf(feat);
        f32x2 fs2; fs2[0] = fs; fs2[1] = fs;

        Frag A0, A1;
#pragma unroll
        for (int p = 0; p < 4; ++p) {
            f32x2 a = fs2 * E0v[p];
            f32x2 c = fs2 * E1v[p];
            A0.u[p] = pack_bf16(a[0], a[1]);
            A1.u[p] = pack_bf16(c[0], c[1]);
        }

        acc = __builtin_amdgcn_mfma_f32_32x32x16_bf16(A0.v, B0.v, zc, 0, 0, 0);
        acc = __builtin_amdgcn_mfma_f32_32x32x16_bf16(A1.v, B1.v, acc, 0, 0, 0);

        if ((k & 3) == 3) {                // group-end renorm (proxy M[2][0])
            int pb = __builtin_amdgcn_readlane(__float_as_int(acc[2]), 0);
            int e  = ((pb >> 23) & 0xff) - 127;
            sc = __int_as_float((127 - e) << 23);   // exact 2^-e
            Cap += e;
            elast = e;
        }

        if (refill) ring[k] = em[(s + 8) * LL];

        // next B operand: direct reg feed (sigma layout), pack only
#pragma unroll
        for (int p = 0; p < 4; ++p) {
            B0.u[p] = pack_bf16(acc[2 * p],     acc[2 * p + 1]);
            B1.u[p] = pack_bf16(acc[8 + 2 * p], acc[9 + 2 * p]);
        }
    };

    for (int s0 = 0; s0 < CL - 8; s0 += 8) {
#pragma unroll
        for (int k = 0; k < 8; ++k) {
            step(B0a, B1a, accA, ringA, scA, CapA, elA, emA,  k, s0 + k, true);
            step(B0b, B1b, accB, ringB, scB, CapB, elB, emBp, k, s0 + k, true);
        }
    }
#pragma unroll
    for (int k = 0; k < 8; ++k) {
        step(B0a, B1a, accA, ringA, scA, CapA, elA, emA,  k, CL - 8 + k, false);
        step(B0b, B1b, accB, ringB, scB, CapB, elB, emBp, k, CL - 8 + k, false);
    }

    CapA -= elA;                           // final measured e never applied
    CapB -= elB;
    if (lane == 0) { capArr[2 * w] = CapA; capArr[2 * w + 1] = CapB; }

    // ---- phase A: waves 0-3 deposit chunks 0..7 (f32, padded stride) ----
    if (w < 4) {
#pragma unroll
        for (int r = 0; r < 16; ++r) {
            int row = (r & 3) + 8 * (r >> 2) + 4 * h;
            shM[2 * w][row * MS + j]     = accA[r];
            shM[2 * w + 1][row * MS + j] = accB[r];
        }
    }

    // wave-0 combine state (registers persist across both phases)
    const float Eend = __expf(transitions[32 + j]);   // exp(trans[END][j])
    float q  = (j == 0) ? 1.0f : 0.0f;                // one-hot SOS
    int   Cq = 0;

    auto combine8 = [&](int base) {
#pragma unroll
        for (int c = 0; c < NCH; ++c) {
            shQ[c & 1][lane] = q;
            asm volatile("s_waitcnt lgkmcnt(0)" ::: "memory");
            __builtin_amdgcn_wave_barrier();
            const float* Mrow = &shM[c][j * MS];
            const float* qv   = &shQ[c & 1][h * 32];
            float a0 = 0.f, a1 = 0.f, a2 = 0.f, a3 = 0.f;
#pragma unroll
            for (int i = 0; i < 32; i += 4) {
                a0 = fmaf(Mrow[i],     qv[i],     a0);
                a1 = fmaf(Mrow[i + 1], qv[i + 1], a1);
                a2 = fmaf(Mrow[i + 2], qv[i + 2], a2);
                a3 = fmaf(Mrow[i + 3], qv[i + 3], a3);
            }
            float qn = (a0 + a1) + (a2 + a3);
            int pb = __builtin_amdgcn_readlane(__float_as_int(qn), 2);
            int e  = ((pb >> 23) & 0xff) - 127;
            qn *= __int_as_float((127 - e) << 23);        // exact 2^-e
            Cq += e + capArr[base + c];
            q = qn;
        }
    };

    __syncthreads();

    if (w == 0) combine8(0);               // fold chunks 0..7

    __syncthreads();

    // ---- phase B: waves 4-7 deposit chunks 8..15 into the same slots ----
    if (w >= 4) {
#pragma unroll
        for (int r = 0; r < 16; ++r) {
            int row = (r & 3) + 8 * (r >> 2) + 4 * h;
            shM[2 * (w - 4)][row * MS + j]     = accA[r];
            shM[2 * (w - 4) + 1][row * MS + j] = accB[r];
        }
    }

    __syncthreads();

    if (w == 0) {
        combine8(NCH);                     // fold chunks 8..15

        float gold = 0.0f;
#pragma unroll
        for (int c = 0; c < NW; ++c) gold += tgArr[c];

        float v = q * Eend;
#pragma unroll
        for (int m = 16; m >= 1; m >>= 1) v += __shfl_xor(v, m, 32);
        float fwd = __logf(v) + (float)Cq * 0.69314718055994531f;

        if (lane == 0) atomicAdd(out, fwd - gold);
    }
}

extern "C" void kernel_launch(void* const* d_in, const int* in_sizes, int n_in,
                              void* d_out, int out_size, void* d_ws, size_t ws_size,
                              hipStream_t stream)
{
    const float* emission    = (const float*)d_in[0];
    const int*   label_ids   = (const int*)d_in[1];
    const float* transitions = (const float*)d_in[2];
    float* out = (float*)d_out;

    (void)hipMemsetAsync(out, 0, sizeof(float), stream);
    crf_fused_kernel<<<BB, NW * 64, 0, stream>>>(emission, label_ids, transitions, out);
}

// Round 3
// 138.719 us; speedup vs baseline: 1.0593x; 1.0043x over previous
//
#include <hip/hip_runtime.h>

// CRF loss: sum_b(forward_score[b] - gold_score[b]).  B=512, T=1024, L=32.
//
// R11 = R8b (proven 64us kernel) + VGPR-pinned accumulators (AGPR-tax fix).
// Post-mortems:
//  - R9 (16 waves, bounds(1024,8)): VGPR cap 64 -> scratch spills (WRITE_SIZE
//    20.9MB). Occupancy axis is register-walled.
//  - R10 (dual chain/wave): fit, but slower (81us) and VGPR_Count=60 proves
//    the compiler runs accumulators in AGPR-split form. Measured ~65 VALU
//    instr/step vs ~25 in source: the gap is v_accvgpr_read feeding the
//    B-pack v_perms + C-tuple re-zeroing. Dual chains doubled that tax.
// R11 pins acc and zc to the arch-VGPR class with empty asm ("+v") - zero
// instructions, forces pure-VGPR MFMA form on the unified gfx950 file.
// Live set ~90 regs fits the 128-reg budget of launch_bounds(512,4).
// Everything else is R8b verbatim: one block/batch, 8 waves x 128 steps,
// 2 chained mfma_32x32x16_bf16/step, sigma-permuted E, acc->B direct feed,
// f32x2 v_pk_mul diet, ring-8 refill with tail split, renorm every 4 steps
// via proxy exponent of M[2][0] (last e un-applied), s_sleep wave skew,
// LDS f32 combine by wave 0.

typedef float  f32x16 __attribute__((ext_vector_type(16)));
typedef short  s16x8  __attribute__((ext_vector_type(8)));
typedef float  f32x2  __attribute__((ext_vector_type(2)));

#define TT 1024
#define LL 32
#define BB 512
#define NC 8
#define CL 128
#define MS 33

union Frag { s16x8 v; unsigned u[4]; };

// pack two f32 -> u32 holding 2 bf16 (truncation): lo in [15:0], hi in [31:16]
__device__ __forceinline__ unsigned pack_bf16(float lo, float hi) {
    return __builtin_amdgcn_perm(__float_as_uint(hi), __float_as_uint(lo), 0x07060302u);
}

__device__ __forceinline__ void skew_sleep(int n) {
    switch (n & 3) {
        case 1: __builtin_amdgcn_s_sleep(1); break;
        case 2: __builtin_amdgcn_s_sleep(2); break;
        case 3: __builtin_amdgcn_s_sleep(3); break;
        default: break;
    }
}

__global__ __launch_bounds__(NC * 64, 4) void crf_fused_kernel(
    const float* __restrict__ emission,    // [B, T, L]
    const int*   __restrict__ label_ids,   // [B, T]
    const float* __restrict__ transitions, // [L, L]
    float*       __restrict__ out)         // [1], pre-zeroed
{
    __shared__ __align__(16) float shM[NC][32 * MS];   // 33,792 B
    __shared__ float shQ[2][64];
    __shared__ float tgArr[NC];
    __shared__ int   capArr[NC];

    const int tid  = threadIdx.x;
    const int w    = tid >> 6;             // wave id = chunk id
    const int lane = tid & 63;
    const int j    = lane & 31;            // A row m / C-D col n
    const int h    = lane >> 5;            // k-half
    const int b    = blockIdx.x;
    const int t0   = w * CL;

    const int*   labB = label_ids + b * TT + t0;
    const float* emB  = emission + ((size_t)b * TT + t0) * LL + j;

    // ---- gold score partial (transitions + emission gather), preamble ----
    {
        float g = 0.0f;
#pragma unroll
        for (int u = 0; u < 2; ++u) {
            int tt = t0 + 64 * u + lane;
            int l1 = labB[64 * u + lane];
            int l0 = (tt == 0) ? 0 : label_ids[b * TT + tt - 1];   // SOS at -1
            g += transitions[(l1 << 5) + l0];
            g += emission[((size_t)b * TT + tt) * LL + l1];
            if (tt == TT - 1) g += transitions[32 + l1];           // trans[END,last]
        }
#pragma unroll
        for (int m = 32; m >= 1; m >>= 1) g += __shfl_xor(g, m, 64);
        if (lane == 0) tgArr[w] = g;
    }

    // ---- E, sigma-permuted cols, as f32x2 pairs for v_pk_mul_f32 ----
    const float* trow = transitions + j * 32;
    f32x2 E0v[4], E1v[4];
#pragma unroll
    for (int p = 0; p < 4; ++p) {
        int c0 = ((2 * p) & 3)     + 8 * ((2 * p) >> 2)     + 4 * h;
        int c1 = ((2 * p + 1) & 3) + 8 * ((2 * p + 1) >> 2) + 4 * h;
        E0v[p][0] = __expf(trow[c0]);      E0v[p][1] = __expf(trow[c1]);
        E1v[p][0] = __expf(trow[16 + c0]); E1v[p][1] = __expf(trow[16 + c1]);
    }

    // ---- B = identity in sigma layout (bf16 1.0 = 0x3F80) ----
    Frag B0, B1;
#pragma unroll
    for (int i = 0; i < 8; ++i) {
        int row = (i & 3) + 8 * (i >> 2) + 4 * h;
        B0.v[i] = (short)((row == j)      ? 0x3F80 : 0);
        B1.v[i] = (short)((row + 16 == j) ? 0x3F80 : 0);
    }

    f32x16 zc, acc;
#pragma unroll
    for (int i = 0; i < 16; ++i) zc[i] = 0.0f;
    // Pin the zero-C tuple to arch VGPRs (unified file) - kills the per-step
    // AGPR C re-materialization the R8b/R10 counters exposed.
    asm volatile("" : "+v"(zc));

    float ring[8];
#pragma unroll
    for (int s = 0; s < 8; ++s) ring[s] = emB[s * LL];

    float sc = 1.0f;
    int   Cap = 0, elast = 0;

    // ---- de-phase the 4 waves/SIMD (one-time, s_sleep = 64*N cyc) ----
    skew_sleep(w + ((blockIdx.x & 1) << 1));

    // one recurrence step; refill only when told (tail has none)
    auto step = [&](int k, int s, bool refill) {
        float feat = ring[k];
        float fs = ((k & 3) == 0) ? (__expf(feat) * sc) : __expf(feat);
        f32x2 fs2; fs2[0] = fs; fs2[1] = fs;

        Frag A0, A1;
#pragma unroll
        for (int p = 0; p < 4; ++p) {
            f32x2 a = fs2 * E0v[p];
            f32x2 c = fs2 * E1v[p];
            A0.u[p] = pack_bf16(a[0], a[1]);
            A1.u[p] = pack_bf16(c[0], c[1]);
        }

        acc = __builtin_amdgcn_mfma_f32_32x32x16_bf16(A0.v, B0.v, zc, 0, 0, 0);
        acc = __builtin_amdgcn_mfma_f32_32x32x16_bf16(A1.v, B1.v, acc, 0, 0, 0);
        // Pin acc to arch VGPRs: the B-pack v_perms and v_readlane read it
        // directly, no v_accvgpr_read hop on the critical path.
        asm volatile("" : "+v"(acc));

        if ((k & 3) == 3) {                // group-end renorm (proxy M[2][0])
            int pb = __builtin_amdgcn_readlane(__float_as_int(acc[2]), 0);
            int e  = ((pb >> 23) & 0xff) - 127;
            sc = __int_as_float((127 - e) << 23);   // exact 2^-e
            Cap += e;
            elast = e;
        }

        if (refill) ring[k] = emB[(s + 8) * LL];

        // next B operand: direct reg feed (sigma layout), pack only
#pragma unroll
        for (int p = 0; p < 4; ++p) {
            B0.u[p] = pack_bf16(acc[2 * p],     acc[2 * p + 1]);
            B1.u[p] = pack_bf16(acc[8 + 2 * p], acc[9 + 2 * p]);
        }
    };

    for (int s0 = 0; s0 < CL - 8; s0 += 8) {
#pragma unroll
        for (int k = 0; k < 8; ++k) step(k, s0 + k, true);
    }
#pragma unroll
    for (int k = 0; k < 8; ++k) step(k, CL - 8 + k, false);

    Cap -= elast;                          // final measured e never applied

    // ---- store M_c to LDS (f32, padded stride -> conflict-free) ----
#pragma unroll
    for (int r = 0; r < 16; ++r) {
        int row = (r & 3) + 8 * (r >> 2) + 4 * h;
        shM[w][row * MS + j] = acc[r];
    }
    if (lane == 0) capArr[w] = Cap;

    __syncthreads();

    // ---- wave 0: sequential 8-chunk matvec combine ----
    if (w == 0) {
        const float Eend = __expf(transitions[32 + j]);   // exp(trans[END][j])
        float q = (j == 0) ? 1.0f : 0.0f;                 // one-hot SOS
        int   Cq = 0;
        float gold = 0.0f;

#pragma unroll
        for (int c = 0; c < NC; ++c) {
            shQ[c & 1][lane] = q;
            asm volatile("s_waitcnt lgkmcnt(0)" ::: "memory");
            __builtin_amdgcn_wave_barrier();
            const float* Mrow = &shM[c][j * MS];
            const float* qv   = &shQ[c & 1][h * 32];
            float a0 = 0.f, a1 = 0.f, a2 = 0.f, a3 = 0.f;
#pragma unroll
            for (int i = 0; i < 32; i += 4) {
                a0 = fmaf(Mrow[i],     qv[i],     a0);
                a1 = fmaf(Mrow[i + 1], qv[i + 1], a1);
                a2 = fmaf(Mrow[i + 2], qv[i + 2], a2);
                a3 = fmaf(Mrow[i + 3], qv[i + 3], a3);
            }
            float qn = (a0 + a1) + (a2 + a3);
            int pb = __builtin_amdgcn_readlane(__float_as_int(qn), 2);
            int e  = ((pb >> 23) & 0xff) - 127;
            qn *= __int_as_float((127 - e) << 23);        // exact 2^-e
            Cq += e + capArr[c];
            gold += tgArr[c];
            q = qn;
        }

        float v = q * Eend;
#pragma unroll
        for (int m = 16; m >= 1; m >>= 1) v += __shfl_xor(v, m, 32);
        float fwd = __logf(v) + (float)Cq * 0.69314718055994531f;

        if (lane == 0) atomicAdd(out, fwd - gold);
    }
}

extern "C" void kernel_launch(void* const* d_in, const int* in_sizes, int n_in,
                              void* d_out, int out_size, void* d_ws, size_t ws_size,
                              hipStream_t stream)
{
    const float* emission    = (const float*)d_in[0];
    const int*   label_ids   = (const int*)d_in[1];
    const float* transitions = (const float*)d_in[2];
    float* out = (float*)d_out;

    (void)hipMemsetAsync(out, 0, sizeof(float), stream);
    crf_fused_kernel<<<BB, NC * 64, 0, stream>>>(emission, label_ids, transitions, out);
}

// Round 4
// 137.753 us; speedup vs baseline: 1.0667x; 1.0070x over previous
//
#include <hip/hip_runtime.h>

// CRF loss: sum_b(forward_score[b] - gold_score[b]).  B=512, T=1024, L=32.
//
// R12 = R8b structure + 256-VGPR budget (registers-for-occupancy trade).
// Post-mortem chain:
//  - Counters (R8b/R11, self-consistent under per-CU normalization): MFMA is
//    only ~5% of issue capacity; VALU runs ~65 instr/step vs ~27 in source.
//    The 2.4x inflation is AGPR cross-file traffic: live set ~90 f32 > the
//    64-VGPR arch allocation the compiler picks under launch_bounds(512,4)'s
//    128-reg cap. R11's "+v" pin couldn't fix it (no room for an all-VGPR
//    solution at 128 regs -> constraint legalized with MORE copies).
//  - R9 proved the occupancy axis is register-walled from the other side.
// R12: __launch_bounds__(512, 2) -> 256-reg budget, full live set in arch
// VGPRs, AGPR split unnecessary. Cost: 1 block/CU (grid = 2 rounds). Issue
// math: per-step/wave 146 -> ~70 cyc; 2 waves/SIMD x 70 = 140 cyc/slot vs
// depth-8 prefetch floor ~112 -> predict ~15-27us kernel.
// Skew: SIMD now hosts waves w, w+4 -> de-phase via (w>>2); block parity
// term dropped (1 block/CU).
// Everything else is R8b verbatim (proven exact): one block/batch, 8 waves x
// 128 steps, 2 chained mfma_32x32x16_bf16/step, sigma-permuted E, acc->B
// direct feed, f32x2 v_pk_mul diet, ring-8 refill with tail split, renorm
// every 4 steps via proxy exponent of M[2][0] (last e un-applied), LDS f32
// combine by wave 0.

typedef float  f32x16 __attribute__((ext_vector_type(16)));
typedef short  s16x8  __attribute__((ext_vector_type(8)));
typedef float  f32x2  __attribute__((ext_vector_type(2)));

#define TT 1024
#define LL 32
#define BB 512
#define NC 8
#define CL 128
#define MS 33

union Frag { s16x8 v; unsigned u[4]; };

// pack two f32 -> u32 holding 2 bf16 (truncation): lo in [15:0], hi in [31:16]
__device__ __forceinline__ unsigned pack_bf16(float lo, float hi) {
    return __builtin_amdgcn_perm(__float_as_uint(hi), __float_as_uint(lo), 0x07060302u);
}

__device__ __forceinline__ void skew_sleep(int n) {
    switch (n & 3) {
        case 1: __builtin_amdgcn_s_sleep(1); break;
        case 2: __builtin_amdgcn_s_sleep(2); break;
        case 3: __builtin_amdgcn_s_sleep(3); break;
        default: break;
    }
}

__global__ __launch_bounds__(NC * 64, 2) void crf_fused_kernel(
    const float* __restrict__ emission,    // [B, T, L]
    const int*   __restrict__ label_ids,   // [B, T]
    const float* __restrict__ transitions, // [L, L]
    float*       __restrict__ out)         // [1], pre-zeroed
{
    __shared__ __align__(16) float shM[NC][32 * MS];   // 33,792 B
    __shared__ float shQ[2][64];
    __shared__ float tgArr[NC];
    __shared__ int   capArr[NC];

    const int tid  = threadIdx.x;
    const int w    = tid >> 6;             // wave id = chunk id
    const int lane = tid & 63;
    const int j    = lane & 31;            // A row m / C-D col n
    const int h    = lane >> 5;            // k-half
    const int b    = blockIdx.x;
    const int t0   = w * CL;

    const int*   labB = label_ids + b * TT + t0;
    const float* emB  = emission + ((size_t)b * TT + t0) * LL + j;

    // ---- gold score partial (transitions + emission gather), preamble ----
    {
        float g = 0.0f;
#pragma unroll
        for (int u = 0; u < 2; ++u) {
            int tt = t0 + 64 * u + lane;
            int l1 = labB[64 * u + lane];
            int l0 = (tt == 0) ? 0 : label_ids[b * TT + tt - 1];   // SOS at -1
            g += transitions[(l1 << 5) + l0];
            g += emission[((size_t)b * TT + tt) * LL + l1];
            if (tt == TT - 1) g += transitions[32 + l1];           // trans[END,last]
        }
#pragma unroll
        for (int m = 32; m >= 1; m >>= 1) g += __shfl_xor(g, m, 64);
        if (lane == 0) tgArr[w] = g;
    }

    // ---- E, sigma-permuted cols, as f32x2 pairs for v_pk_mul_f32 ----
    const float* trow = transitions + j * 32;
    f32x2 E0v[4], E1v[4];
#pragma unroll
    for (int p = 0; p < 4; ++p) {
        int c0 = ((2 * p) & 3)     + 8 * ((2 * p) >> 2)     + 4 * h;
        int c1 = ((2 * p + 1) & 3) + 8 * ((2 * p + 1) >> 2) + 4 * h;
        E0v[p][0] = __expf(trow[c0]);      E0v[p][1] = __expf(trow[c1]);
        E1v[p][0] = __expf(trow[16 + c0]); E1v[p][1] = __expf(trow[16 + c1]);
    }

    // ---- B = identity in sigma layout (bf16 1.0 = 0x3F80) ----
    Frag B0, B1;
#pragma unroll
    for (int i = 0; i < 8; ++i) {
        int row = (i & 3) + 8 * (i >> 2) + 4 * h;
        B0.v[i] = (short)((row == j)      ? 0x3F80 : 0);
        B1.v[i] = (short)((row + 16 == j) ? 0x3F80 : 0);
    }

    f32x16 zc, acc;
#pragma unroll
    for (int i = 0; i < 16; ++i) zc[i] = 0.0f;
    // Keep the VGPR-class pin (free; with a 256-reg budget the allocator now
    // has room to honor it without compensating copies).
    asm volatile("" : "+v"(zc));

    float ring[8];
#pragma unroll
    for (int s = 0; s < 8; ++s) ring[s] = emB[s * LL];

    float sc = 1.0f;
    int   Cap = 0, elast = 0;

    // ---- de-phase the 2 waves/SIMD (SIMD hosts waves w and w+4) ----
    skew_sleep(w >> 2);

    // one recurrence step; refill only when told (tail has none)
    auto step = [&](int k, int s, bool refill) {
        float feat = ring[k];
        float fs = ((k & 3) == 0) ? (__expf(feat) * sc) : __expf(feat);
        f32x2 fs2; fs2[0] = fs; fs2[1] = fs;

        Frag A0, A1;
#pragma unroll
        for (int p = 0; p < 4; ++p) {
            f32x2 a = fs2 * E0v[p];
            f32x2 c = fs2 * E1v[p];
            A0.u[p] = pack_bf16(a[0], a[1]);
            A1.u[p] = pack_bf16(c[0], c[1]);
        }

        acc = __builtin_amdgcn_mfma_f32_32x32x16_bf16(A0.v, B0.v, zc, 0, 0, 0);
        acc = __builtin_amdgcn_mfma_f32_32x32x16_bf16(A1.v, B1.v, acc, 0, 0, 0);
        asm volatile("" : "+v"(acc));

        if ((k & 3) == 3) {                // group-end renorm (proxy M[2][0])
            int pb = __builtin_amdgcn_readlane(__float_as_int(acc[2]), 0);
            int e  = ((pb >> 23) & 0xff) - 127;
            sc = __int_as_float((127 - e) << 23);   // exact 2^-e
            Cap += e;
            elast = e;
        }

        if (refill) ring[k] = emB[(s + 8) * LL];

        // next B operand: direct reg feed (sigma layout), pack only
#pragma unroll
        for (int p = 0; p < 4; ++p) {
            B0.u[p] = pack_bf16(acc[2 * p],     acc[2 * p + 1]);
            B1.u[p] = pack_bf16(acc[8 + 2 * p], acc[9 + 2 * p]);
        }
    };

    for (int s0 = 0; s0 < CL - 8; s0 += 8) {
#pragma unroll
        for (int k = 0; k < 8; ++k) step(k, s0 + k, true);
    }
#pragma unroll
    for (int k = 0; k < 8; ++k) step(k, CL - 8 + k, false);

    Cap -= elast;                          // final measured e never applied

    // ---- store M_c to LDS (f32, padded stride -> conflict-free) ----
#pragma unroll
    for (int r = 0; r < 16; ++r) {
        int row = (r & 3) + 8 * (r >> 2) + 4 * h;
        shM[w][row * MS + j] = acc[r];
    }
    if (lane == 0) capArr[w] = Cap;

    __syncthreads();

    // ---- wave 0: sequential 8-chunk matvec combine ----
    if (w == 0) {
        const float Eend = __expf(transitions[32 + j]);   // exp(trans[END][j])
        float q = (j == 0) ? 1.0f : 0.0f;                 // one-hot SOS
        int   Cq = 0;
        float gold = 0.0f;

#pragma unroll
        for (int c = 0; c < NC; ++c) {
            shQ[c & 1][lane] = q;
            asm volatile("s_waitcnt lgkmcnt(0)" ::: "memory");
            __builtin_amdgcn_wave_barrier();
            const float* Mrow = &shM[c][j * MS];
            const float* qv   = &shQ[c & 1][h * 32];
            float a0 = 0.f, a1 = 0.f, a2 = 0.f, a3 = 0.f;
#pragma unroll
            for (int i = 0; i < 32; i += 4) {
                a0 = fmaf(Mrow[i],     qv[i],     a0);
                a1 = fmaf(Mrow[i + 1], qv[i + 1], a1);
                a2 = fmaf(Mrow[i + 2], qv[i + 2], a2);
                a3 = fmaf(Mrow[i + 3], qv[i + 3], a3);
            }
            float qn = (a0 + a1) + (a2 + a3);
            int pb = __builtin_amdgcn_readlane(__float_as_int(qn), 2);
            int e  = ((pb >> 23) & 0xff) - 127;
            qn *= __int_as_float((127 - e) << 23);        // exact 2^-e
            Cq += e + capArr[c];
            gold += tgArr[c];
            q = qn;
        }

        float v = q * Eend;
#pragma unroll
        for (int m = 16; m >= 1; m >>= 1) v += __shfl_xor(v, m, 32);
        float fwd = __logf(v) + (float)Cq * 0.69314718055994531f;

        if (lane == 0) atomicAdd(out, fwd - gold);
    }
}

extern "C" void kernel_launch(void* const* d_in, const int* in_sizes, int n_in,
                              void* d_out, int out_size, void* d_ws, size_t ws_size,
                              hipStream_t stream)
{
    const float* emission    = (const float*)d_in[0];
    const int*   label_ids   = (const int*)d_in[1];
    const float* transitions = (const float*)d_in[2];
    float* out = (float*)d_out;

    (void)hipMemsetAsync(out, 0, sizeof(float), stream);
    crf_fused_kernel<<<BB, NC * 64, 0, stream>>>(emission, label_ids, transitions, out);
}